// Round 2
// baseline (2715.283 us; speedup 1.0000x reference)
//
#include <hip/hip_runtime.h>
#include <math.h>
#include <stdint.h>

// ---------------- JAX threefry2x32 (key = [0,42]) + normal transform ----------------
__device__ __forceinline__ void threefry2x32_42(uint32_t x0, uint32_t x1,
                                                uint32_t& o0, uint32_t& o1) {
  const uint32_t k0 = 0u, k1 = 42u;
  const uint32_t k2 = k0 ^ k1 ^ 0x1BD11BDAu;
  x0 += k0; x1 += k1;
#define TF_R(r) { x0 += x1; x1 = (x1 << (r)) | (x1 >> (32 - (r))); x1 ^= x0; }
  TF_R(13) TF_R(15) TF_R(26) TF_R(6)
  x0 += k1; x1 += k2 + 1u;
  TF_R(17) TF_R(29) TF_R(16) TF_R(24)
  x0 += k2; x1 += k0 + 2u;
  TF_R(13) TF_R(15) TF_R(26) TF_R(6)
  x0 += k0; x1 += k1 + 3u;
  TF_R(17) TF_R(29) TF_R(16) TF_R(24)
  x0 += k1; x1 += k2 + 4u;
  TF_R(13) TF_R(15) TF_R(26) TF_R(6)
  x0 += k2; x1 += k0 + 5u;
#undef TF_R
  o0 = x0; o1 = x1;
}

// XLA ErfInv32 (Giles 2012), strict mul/add ordering (no FMA contraction).
__device__ __forceinline__ float jax_erfinv_f32(float x) {
  float xx = __fmul_rn(x, x);
  float w = -log1pf(-xx);
  float p;
  if (w < 5.0f) {
    w = __fadd_rn(w, -2.5f);
    p = 2.81022636e-08f;
    p = __fadd_rn(3.43273939e-07f, __fmul_rn(p, w));
    p = __fadd_rn(-3.5233877e-06f, __fmul_rn(p, w));
    p = __fadd_rn(-4.39150654e-06f, __fmul_rn(p, w));
    p = __fadd_rn(0.00021858087f, __fmul_rn(p, w));
    p = __fadd_rn(-0.00125372503f, __fmul_rn(p, w));
    p = __fadd_rn(-0.00417768164f, __fmul_rn(p, w));
    p = __fadd_rn(0.246640727f, __fmul_rn(p, w));
    p = __fadd_rn(1.50140941f, __fmul_rn(p, w));
  } else {
    w = __fadd_rn(sqrtf(w), -3.0f);
    p = -0.000200214257f;
    p = __fadd_rn(0.000100950558f, __fmul_rn(p, w));
    p = __fadd_rn(0.00134934322f, __fmul_rn(p, w));
    p = __fadd_rn(-0.00367342844f, __fmul_rn(p, w));
    p = __fadd_rn(0.00573950773f, __fmul_rn(p, w));
    p = __fadd_rn(-0.0076224613f, __fmul_rn(p, w));
    p = __fadd_rn(0.00943887047f, __fmul_rn(p, w));
    p = __fadd_rn(1.00167406f, __fmul_rn(p, w));
    p = __fadd_rn(2.83297682f, __fmul_rn(p, w));
  }
  return __fmul_rn(p, x);
}

// noise[n], flattened index n over shape (4,2048,8).
// JAX >= 0.4.30 default: jax_threefry_partitionable=True ->
// per-element 64-bit counter (hi=0, lo=n); 32-bit bits = out0 ^ out1.
__device__ __forceinline__ float jax_noise(uint32_t n) {
  uint32_t o0, o1;
  threefry2x32_42(0u, n, o0, o1);
  uint32_t bits = o0 ^ o1;
  uint32_t fb = (bits >> 9) | 0x3F800000u;              // [1,2)
  float f = __fadd_rn(__uint_as_float(fb), -1.0f);      // [0,1)
  const float lo = __uint_as_float(0xBF7FFFFFu);        // nextafter(-1,0)
  float u = __fadd_rn(__fmul_rn(f, 2.0f), lo);          // maxval-minval == 2.0f exactly
  u = fmaxf(lo, u);
  return __fmul_rn(__uint_as_float(0x3FB504F3u), jax_erfinv_f32(u));  // sqrt(2)*erfinv(u)
}

// ---------------- block reduction helper (256 threads = 4 waves) ----------------
__device__ __forceinline__ float block_sum_256(float v, float* buf) {
  #pragma unroll
  for (int off = 32; off > 0; off >>= 1) v += __shfl_down(v, off, 64);
  int lane = threadIdx.x & 63;
  int w = threadIdx.x >> 6;
  if (lane == 0) buf[w] = v;
  __syncthreads();
  return buf[0] + buf[1] + buf[2] + buf[3];
}

// ---------------- kernel 1: embed + LN1 ----------------
__global__ __launch_bounds__(256) void k_embed_ln1(
    const int* __restrict__ idx, const float* __restrict__ tok,
    const float* __restrict__ pos, const float* __restrict__ g1,
    const float* __restrict__ b1, float* __restrict__ x_out,
    float* __restrict__ xn_out) {
  __shared__ float bufA[4], bufB[4];
  int r = blockIdx.x;            // 0..8191 (b*2048+t)
  int t = r & 2047;
  int token = idx[r];
  int c4 = threadIdx.x;          // one float4 per thread (1024 = 256*4)
  float4 tv = *((const float4*)(tok + (size_t)token * 1024) + c4);
  float4 pv = *((const float4*)(pos + (size_t)t * 1024) + c4);
  float4 xv = make_float4(tv.x + pv.x, tv.y + pv.y, tv.z + pv.z, tv.w + pv.w);
  *((float4*)(x_out + (size_t)r * 1024) + c4) = xv;
  float mu = block_sum_256(xv.x + xv.y + xv.z + xv.w, bufA) * (1.0f / 1024.0f);
  float d0 = xv.x - mu, d1 = xv.y - mu, d2 = xv.z - mu, d3 = xv.w - mu;
  float var = block_sum_256(d0*d0 + d1*d1 + d2*d2 + d3*d3, bufB) * (1.0f / 1024.0f);
  float rs = rsqrtf(var + 1e-5f);
  float4 gv = *((const float4*)g1 + c4);
  float4 bv = *((const float4*)b1 + c4);
  float4 xn = make_float4(d0*rs*gv.x + bv.x, d1*rs*gv.y + bv.y,
                          d2*rs*gv.z + bv.z, d3*rs*gv.w + bv.w);
  *((float4*)(xn_out + (size_t)r * 1024) + c4) = xn;
}

// ---------------- kernel 5: LN2 ----------------
__global__ __launch_bounds__(256) void k_ln2(
    const float* __restrict__ x, const float* __restrict__ g2,
    const float* __restrict__ b2, float* __restrict__ xn_out) {
  __shared__ float bufA[4], bufB[4];
  int r = blockIdx.x;
  int c4 = threadIdx.x;
  float4 xv = *((const float4*)(x + (size_t)r * 1024) + c4);
  float mu = block_sum_256(xv.x + xv.y + xv.z + xv.w, bufA) * (1.0f / 1024.0f);
  float d0 = xv.x - mu, d1 = xv.y - mu, d2 = xv.z - mu, d3 = xv.w - mu;
  float var = block_sum_256(d0*d0 + d1*d1 + d2*d2 + d3*d3, bufB) * (1.0f / 1024.0f);
  float rs = rsqrtf(var + 1e-5f);
  float4 gv = *((const float4*)g2 + c4);
  float4 bv = *((const float4*)b2 + c4);
  float4 xn = make_float4(d0*rs*gv.x + bv.x, d1*rs*gv.y + bv.y,
                          d2*rs*gv.z + bv.z, d3*rs*gv.w + bv.w);
  *((float4*)(xn_out + (size_t)r * 1024) + c4) = xn;
}

// ---------------- kernel 2: QKV projection, per-head GEMM 8192x128x1024 ----------------
// grid (128, 24): y -> which(0=q,1=k,2=v) * head; 64x128 tile, 256 threads, 4x8/thread.
__global__ __launch_bounds__(256) void k_qkv(
    const float* __restrict__ xn, const float* __restrict__ Wq,
    const float* __restrict__ Wk, const float* __restrict__ Wv,
    float* __restrict__ q, float* __restrict__ k, float* __restrict__ v) {
  __shared__ float AsT[16][68];   // [kk][row], padded
  __shared__ float Bs[16][128];
  int z = blockIdx.y;
  int which = z >> 3, h = z & 7;
  const float* Wsel = (which == 0) ? Wq : (which == 1) ? Wk : Wv;
  const float* B = Wsel + (size_t)h * (1024 * 128);
  float* Out = (which == 0) ? q : (which == 1) ? k : v;
  int m0 = blockIdx.x * 64;
  int tid = threadIdx.x;
  int tx = tid & 15, ty = tid >> 4;
  float acc[4][8];
  #pragma unroll
  for (int i = 0; i < 4; ++i)
    #pragma unroll
    for (int j = 0; j < 8; ++j) acc[i][j] = 0.f;
  int arow = tid >> 2, ac4 = (tid & 3) << 2;
  int brow = tid >> 5, bc4 = (tid & 31) << 2;
  for (int k0 = 0; k0 < 1024; k0 += 16) {
    float4 av  = *(const float4*)(xn + (size_t)(m0 + arow) * 1024 + k0 + ac4);
    float4 bv0 = *(const float4*)(B + (size_t)(k0 + brow) * 128 + bc4);
    float4 bv1 = *(const float4*)(B + (size_t)(k0 + 8 + brow) * 128 + bc4);
    __syncthreads();
    AsT[ac4 + 0][arow] = av.x;
    AsT[ac4 + 1][arow] = av.y;
    AsT[ac4 + 2][arow] = av.z;
    AsT[ac4 + 3][arow] = av.w;
    *(float4*)&Bs[brow][bc4] = bv0;
    *(float4*)&Bs[brow + 8][bc4] = bv1;
    __syncthreads();
    #pragma unroll
    for (int kk = 0; kk < 16; ++kk) {
      float a[4];
      #pragma unroll
      for (int i = 0; i < 4; ++i) a[i] = AsT[kk][ty * 4 + i];
      float b[8];
      *(float4*)&b[0] = *(float4*)&Bs[kk][tx * 8];
      *(float4*)&b[4] = *(float4*)&Bs[kk][tx * 8 + 4];
      #pragma unroll
      for (int i = 0; i < 4; ++i)
        #pragma unroll
        for (int j = 0; j < 8; ++j) acc[i][j] += a[i] * b[j];
    }
  }
  #pragma unroll
  for (int i = 0; i < 4; ++i) {
    int m = m0 + ty * 4 + i;
    int bb = m >> 11, t = m & 2047;
    float* orow = Out + ((size_t)((bb * 8 + h) * 2048 + t)) * 128 + tx * 8;
    *(float4*)orow       = make_float4(acc[i][0], acc[i][1], acc[i][2], acc[i][3]);
    *((float4*)orow + 1) = make_float4(acc[i][4], acc[i][5], acc[i][6], acc[i][7]);
  }
}

// ---------------- kernel 4: x += attn @ Wo + bo ----------------
__global__ __launch_bounds__(256) void k_proj_res(
    const float* __restrict__ A, const float* __restrict__ Wo,
    const float* __restrict__ bo, float* __restrict__ x_io) {
  __shared__ float AsT[16][68];
  __shared__ float Bs[16][128];
  int m0 = blockIdx.x * 64;
  int n0 = blockIdx.y * 128;
  int tid = threadIdx.x;
  int tx = tid & 15, ty = tid >> 4;
  float acc[4][8];
  #pragma unroll
  for (int i = 0; i < 4; ++i)
    #pragma unroll
    for (int j = 0; j < 8; ++j) acc[i][j] = 0.f;
  int arow = tid >> 2, ac4 = (tid & 3) << 2;
  int brow = tid >> 5, bc4 = (tid & 31) << 2;
  for (int k0 = 0; k0 < 1024; k0 += 16) {
    float4 av  = *(const float4*)(A + (size_t)(m0 + arow) * 1024 + k0 + ac4);
    float4 bv0 = *(const float4*)(Wo + (size_t)(k0 + brow) * 1024 + n0 + bc4);
    float4 bv1 = *(const float4*)(Wo + (size_t)(k0 + 8 + brow) * 1024 + n0 + bc4);
    __syncthreads();
    AsT[ac4 + 0][arow] = av.x;
    AsT[ac4 + 1][arow] = av.y;
    AsT[ac4 + 2][arow] = av.z;
    AsT[ac4 + 3][arow] = av.w;
    *(float4*)&Bs[brow][bc4] = bv0;
    *(float4*)&Bs[brow + 8][bc4] = bv1;
    __syncthreads();
    #pragma unroll
    for (int kk = 0; kk < 16; ++kk) {
      float a[4];
      #pragma unroll
      for (int i = 0; i < 4; ++i) a[i] = AsT[kk][ty * 4 + i];
      float b[8];
      *(float4*)&b[0] = *(float4*)&Bs[kk][tx * 8];
      *(float4*)&b[4] = *(float4*)&Bs[kk][tx * 8 + 4];
      #pragma unroll
      for (int i = 0; i < 4; ++i)
        #pragma unroll
        for (int j = 0; j < 8; ++j) acc[i][j] += a[i] * b[j];
    }
  }
  float4 bo0 = *(const float4*)(bo + n0 + tx * 8);
  float4 bo1 = *(const float4*)(bo + n0 + tx * 8 + 4);
  #pragma unroll
  for (int i = 0; i < 4; ++i) {
    int m = m0 + ty * 4 + i;
    float* xr = x_io + (size_t)m * 1024 + n0 + tx * 8;
    float4 r0 = *(float4*)xr;
    float4 r1 = *((float4*)xr + 1);
    r0.x += acc[i][0] + bo0.x; r0.y += acc[i][1] + bo0.y;
    r0.z += acc[i][2] + bo0.z; r0.w += acc[i][3] + bo0.w;
    r1.x += acc[i][4] + bo1.x; r1.y += acc[i][5] + bo1.y;
    r1.z += acc[i][6] + bo1.z; r1.w += acc[i][7] + bo1.w;
    *(float4*)xr = r0;
    *((float4*)xr + 1) = r1;
  }
}

// ---------------- kernel 3: causal flash attention ----------------
// grid (64, 8, 4): 32 Q-rows per block, KV tiles of 64. XOR slot swizzle on
// Qs/KVs rows to break the stride-128 16-way bank conflict.
#define SW(r, s) ((((s) ^ ((r) & 31)) << 2))

__global__ __launch_bounds__(256) void k_attn(
    const float* __restrict__ q, const float* __restrict__ k,
    const float* __restrict__ v, float* __restrict__ attn_out) {
  __shared__ float Qs[32][128];
  __shared__ float KVs[64][128];
  __shared__ float Ps[32][68];
  __shared__ float red[32][4];
  __shared__ float mrow[32], lrow[32], arow[32];
  int qt = blockIdx.x, h = blockIdx.y, b = blockIdx.z;
  int t0 = qt * 32;
  const float* qb = q + (size_t)(b * 8 + h) * 2048 * 128;
  const float* kb = k + (size_t)(b * 8 + h) * 2048 * 128;
  const float* vb = v + (size_t)(b * 8 + h) * 2048 * 128;
  int tid = threadIdx.x;
  int tx = tid & 15, ty = tid >> 4;
  #pragma unroll
  for (int i = 0; i < 4; ++i) {
    int f = tid + (i << 8);
    int rr = f >> 5, ss = f & 31;
    *(float4*)&Qs[rr][SW(rr, ss)] =
        *(const float4*)(qb + (size_t)(t0 + rr) * 128 + (ss << 2));
  }
  if (tid < 32) { mrow[tid] = -INFINITY; lrow[tid] = 0.f; }
  float o[2][8];
  #pragma unroll
  for (int i = 0; i < 2; ++i)
    #pragma unroll
    for (int j = 0; j < 8; ++j) o[i][j] = 0.f;
  __syncthreads();
  for (int j0 = 0; j0 <= t0; j0 += 64) {
    // K tile
    #pragma unroll
    for (int i = 0; i < 8; ++i) {
      int f = tid + (i << 8);
      int rr = f >> 5, ss = f & 31;
      *(float4*)&KVs[rr][SW(rr, ss)] =
          *(const float4*)(kb + (size_t)(j0 + rr) * 128 + (ss << 2));
    }
    __syncthreads();
    float s[2][4];
    #pragma unroll
    for (int i = 0; i < 2; ++i)
      #pragma unroll
      for (int j = 0; j < 4; ++j) s[i][j] = 0.f;
    #pragma unroll 8
    for (int dd = 0; dd < 128; dd += 4) {
      int s4 = dd >> 2;
      float4 qv[2], kv[4];
      #pragma unroll
      for (int i = 0; i < 2; ++i) {
        int ri = ty * 2 + i;
        qv[i] = *(float4*)&Qs[ri][SW(ri, s4)];
      }
      #pragma unroll
      for (int j = 0; j < 4; ++j) {
        int cj = tx * 4 + j;
        kv[j] = *(float4*)&KVs[cj][SW(cj, s4)];
      }
      #pragma unroll
      for (int i = 0; i < 2; ++i)
        #pragma unroll
        for (int j = 0; j < 4; ++j)
          s[i][j] += qv[i].x * kv[j].x + qv[i].y * kv[j].y +
                     qv[i].z * kv[j].z + qv[i].w * kv[j].w;
    }
    #pragma unroll
    for (int i = 0; i < 2; ++i) {
      int gr = t0 + ty * 2 + i;
      #pragma unroll
      for (int j = 0; j < 4; ++j) {
        int gc = j0 + tx * 4 + j;
        float sv = s[i][j] * 0.03125f;     // * D^-0.5 = 1/32
        if (gc > gr) sv = -INFINITY;
        Ps[ty * 2 + i][tx * 4 + j] = sv;
      }
    }
    __syncthreads();
    // V tile overwrites K region (K no longer needed); row-max partials in parallel
    #pragma unroll
    for (int i = 0; i < 8; ++i) {
      int f = tid + (i << 8);
      int rr = f >> 5, ss = f & 31;
      *(float4*)&KVs[rr][SW(rr, ss)] =
          *(const float4*)(vb + (size_t)(j0 + rr) * 128 + (ss << 2));
    }
    if (tid < 128) {
      int rr = tid >> 2, qq = tid & 3;
      float mx = -INFINITY;
      #pragma unroll
      for (int c = 0; c < 16; ++c) mx = fmaxf(mx, Ps[rr][qq * 16 + c]);
      red[rr][qq] = mx;
    }
    __syncthreads();
    if (tid < 32) {
      float mo = mrow[tid];
      float mn = fmaxf(fmaxf(red[tid][0], red[tid][1]),
                       fmaxf(red[tid][2], red[tid][3]));
      mn = fmaxf(mo, mn);
      mrow[tid] = mn;
      arow[tid] = expf(mo - mn);
    }
    __syncthreads();
    if (tid < 128) {
      int rr = tid >> 2, qq = tid & 3;
      float mn = mrow[rr];
      float sm = 0.f;
      #pragma unroll
      for (int c = 0; c < 16; ++c) {
        float e = expf(Ps[rr][qq * 16 + c] - mn);
        Ps[rr][qq * 16 + c] = e;
        sm += e;
      }
      red[rr][qq] = sm;
    }
    __syncthreads();
    if (tid < 32)
      lrow[tid] = lrow[tid] * arow[tid] +
                  (red[tid][0] + red[tid][1] + red[tid][2] + red[tid][3]);
    #pragma unroll
    for (int i = 0; i < 2; ++i) {
      float al = arow[ty * 2 + i];
      #pragma unroll
      for (int j = 0; j < 8; ++j) o[i][j] *= al;
    }
    for (int c = 0; c < 64; ++c) {
      int s0 = tx << 1;
      float4 v0 = *(float4*)&KVs[c][SW(c, s0)];
      float4 v1 = *(float4*)&KVs[c][SW(c, s0 | 1)];
      #pragma unroll
      for (int i = 0; i < 2; ++i) {
        float p = Ps[ty * 2 + i][c];
        o[i][0] += p * v0.x; o[i][1] += p * v0.y;
        o[i][2] += p * v0.z; o[i][3] += p * v0.w;
        o[i][4] += p * v1.x; o[i][5] += p * v1.y;
        o[i][6] += p * v1.z; o[i][7] += p * v1.w;
      }
    }
    __syncthreads();
  }
  #pragma unroll
  for (int i = 0; i < 2; ++i) {
    int ri = ty * 2 + i;
    float inv = 1.f / lrow[ri];
    float* orow = attn_out + ((size_t)(b * 2048 + t0 + ri)) * 1024 + h * 128 + tx * 8;
    *(float4*)orow       = make_float4(o[i][0]*inv, o[i][1]*inv, o[i][2]*inv, o[i][3]*inv);
    *((float4*)orow + 1) = make_float4(o[i][4]*inv, o[i][5]*inv, o[i][6]*inv, o[i][7]*inv);
  }
}

// ---------------- kernel 6: noisy top-k router ----------------
// one wave per row; lane 0 does the threefry/top-k tail.
__global__ __launch_bounds__(256) void k_router(
    const float* __restrict__ xn, const float* __restrict__ Wr,
    const float* __restrict__ br, const float* __restrict__ Wn,
    const float* __restrict__ bn, float* __restrict__ rp_out,
    float* __restrict__ idx_out) {
  int wave = threadIdx.x >> 6, lane = threadIdx.x & 63;
  int r = blockIdx.x * 4 + wave;
  const float* xr = xn + (size_t)r * 1024;
  float acc[16];
  #pragma unroll
  for (int i = 0; i < 16; ++i) acc[i] = 0.f;
  int cbase = lane * 16;
  for (int cc = 0; cc < 16; ++cc) {
    int c = cbase + cc;
    float xv = xr[c];
    const float4* wr4 = (const float4*)(Wr + (size_t)c * 8);
    float4 w0 = wr4[0], w1 = wr4[1];
    acc[0] += xv * w0.x; acc[1] += xv * w0.y; acc[2] += xv * w0.z; acc[3] += xv * w0.w;
    acc[4] += xv * w1.x; acc[5] += xv * w1.y; acc[6] += xv * w1.z; acc[7] += xv * w1.w;
    const float4* wn4 = (const float4*)(Wn + (size_t)c * 8);
    float4 n0 = wn4[0], n1 = wn4[1];
    acc[8]  += xv * n0.x; acc[9]  += xv * n0.y; acc[10] += xv * n0.z; acc[11] += xv * n0.w;
    acc[12] += xv * n1.x; acc[13] += xv * n1.y; acc[14] += xv * n1.z; acc[15] += xv * n1.w;
  }
  #pragma unroll
  for (int i = 0; i < 16; ++i) {
    #pragma unroll
    for (int off = 32; off > 0; off >>= 1) acc[i] += __shfl_down(acc[i], off, 64);
  }
  if (lane == 0) {
    float noisy[8];
    uint32_t nbase = (uint32_t)r * 8u;
    #pragma unroll
    for (int e = 0; e < 8; ++e) {
      float lg = acc[e] + br[e];
      float x = acc[8 + e] + bn[e];
      // softplus = logaddexp(x,0) = max(x,0) + log1p(exp(-|x|))
      float sp = __fadd_rn(fmaxf(x, 0.f), log1pf(expf(-fabsf(x))));
      float nz = jax_noise(nbase + (uint32_t)e);
      noisy[e] = __fadd_rn(lg, __fmul_rn(nz, sp));
    }
    float v1 = -INFINITY, v2 = -INFINITY;
    int i1 = 0, i2 = 0;
    #pragma unroll
    for (int e = 0; e < 8; ++e) {
      float vv = noisy[e];
      if (vv > v1) { v2 = v1; i2 = i1; v1 = vv; i1 = e; }
      else if (vv > v2) { v2 = vv; i2 = e; }
    }
    float e2 = expf(v2 - v1);
    float ssum = 1.f + e2;
    float p1 = 1.f / ssum, p2 = e2 / ssum;
    float rp[8];
    #pragma unroll
    for (int e = 0; e < 8; ++e) rp[e] = 0.f;
    rp[i1] = p1; rp[i2] = p2;
    float* op = rp_out + (size_t)r * 8;
    #pragma unroll
    for (int e = 0; e < 8; ++e) op[e] = rp[e];
    idx_out[(size_t)r * 2]     = (float)i1;
    idx_out[(size_t)r * 2 + 1] = (float)i2;
  }
}

// ---------------- launch ----------------
extern "C" void kernel_launch(void* const* d_in, const int* in_sizes, int n_in,
                              void* d_out, int out_size, void* d_ws, size_t ws_size,
                              hipStream_t stream) {
  const int*   idx = (const int*)d_in[0];
  const float* tok = (const float*)d_in[1];
  const float* pos = (const float*)d_in[2];
  const float* Wq  = (const float*)d_in[3];
  const float* Wk  = (const float*)d_in[4];
  const float* Wv  = (const float*)d_in[5];
  const float* Wo  = (const float*)d_in[6];
  const float* bo  = (const float*)d_in[7];
  const float* g1  = (const float*)d_in[8];
  const float* b1  = (const float*)d_in[9];
  const float* g2  = (const float*)d_in[10];
  const float* b2  = (const float*)d_in[11];
  const float* Wr  = (const float*)d_in[12];
  const float* br  = (const float*)d_in[13];
  const float* Wn  = (const float*)d_in[14];
  const float* bn  = (const float*)d_in[15];

  float* out_xnorm = (float*)d_out;             // 4*2048*1024
  float* out_rp    = out_xnorm + 8388608;       // 4*2048*8
  float* out_idx   = out_rp + 65536;            // 4*2048*2 (written as float)
  float* out_x     = out_idx + 16384;           // 4*2048*1024

  float* xn   = (float*)d_ws;                   // 32 MB
  float* qb   = xn + 8388608;                   // 32 MB
  float* kb   = qb + 8388608;                   // 32 MB
  float* vb   = kb + 8388608;                   // 32 MB
  float* attn = xn;                             // reuse xn after QKV

  k_embed_ln1<<<8192, 256, 0, stream>>>(idx, tok, pos, g1, b1, out_x, xn);
  k_qkv<<<dim3(128, 24), 256, 0, stream>>>(xn, Wq, Wk, Wv, qb, kb, vb);
  k_attn<<<dim3(64, 8, 4), 256, 0, stream>>>(qb, kb, vb, attn);
  k_proj_res<<<dim3(128, 8), 256, 0, stream>>>(attn, Wo, bo, out_x);
  k_ln2<<<8192, 256, 0, stream>>>(out_x, g2, b2, out_xnorm);
  k_router<<<2048, 256, 0, stream>>>(out_xnorm, Wr, br, Wn, bn, out_rp, out_idx);
}